// Round 11
// baseline (94.344 us; speedup 1.0000x reference)
//
#include <hip/hip_runtime.h>
#include <math.h>

#define NPOW 86   // power sums S_0..S_85
#define NCO  85   // series coefficients n=0..84

// ws layout:
//   ctx   [32][2][768]  : scene_context | speaker_context
//   final [32][3840]    : [z(2304) | sent_sh(512) | scene_sh(512) | spkr_sh(512)]
//   hpart [32][8][256]  : mlp stage-1 K-split partials

__device__ __forceinline__ double wred(double x) {
    #pragma unroll
    for (int off = 1; off < 64; off <<= 1)
        x += __shfl_xor(x, off, 64);
    return x;
}

// ---- projection helper: [768] x [768,512] with 256 threads, 2-way K-split (r8-verified)
__device__ __forceinline__ void proj_256(
    const float* __restrict__ xsrc,
    const float* __restrict__ Ws,            // [768, 512]
    const float* __restrict__ bs,            // [512]
    float* __restrict__ dst,
    float* xb,                               // LDS [768]
    float* redf,                             // LDS [1024] = [2][512]
    int tid)
{
    for (int i = tid; i < 768; i += 256) xb[i] = xsrc[i];
    __syncthreads();

    const int g = tid >> 7;        // 0..1
    const int q = tid & 127;       // column quad
    const float4* __restrict__ Wv = (const float4*)Ws;   // [768][128]
    float ax = 0.f, ay = 0.f, az = 0.f, aw = 0.f;
    #pragma unroll 8
    for (int k = g; k < 768; k += 2) {
        const float xv = xb[k];
        const float4 w = Wv[k * 128 + q];
        ax += xv * w.x; ay += xv * w.y; az += xv * w.z; aw += xv * w.w;
    }
    redf[g * 512 + q * 4 + 0] = ax;
    redf[g * 512 + q * 4 + 1] = ay;
    redf[g * 512 + q * 4 + 2] = az;
    redf[g * 512 + q * 4 + 3] = aw;
    __syncthreads();

    dst[tid]       = bs[tid]       + redf[tid]       + redf[512 + tid];
    dst[tid + 256] = bs[tid + 256] + redf[tid + 256] + redf[512 + tid + 256];
}

// K1: grid (32,3), 256 threads.
//  y=0: scene ctx  = attn(q=ss, k=ss, v=sd) via power sums S_n=Σ ss^n, T_n=Σ ss^n·sd
//  y=1: spkr ctx   = attn(q=oth, k=tgt, v=tgt) via S_n=Σ tgt^n (v=k → num uses S_{n+1})
//  y=2: sentence projection
__global__ __launch_bounds__(256) void k1_small_kernel(
    const float* __restrict__ sentence,
    const float* __restrict__ target,
    const float* __restrict__ other,
    const float* __restrict__ scene_desc,
    const float* __restrict__ scene_sent,
    const float* __restrict__ Ws,
    const float* __restrict__ bs,
    float* __restrict__ ctx,
    float* __restrict__ final_)
{
    const int b = blockIdx.x;
    const int y = blockIdx.y;
    const int tid = threadIdx.x;
    __shared__ float kb[768];
    __shared__ float vbuf[768];
    __shared__ double part[NPOW][4][2];
    __shared__ double coefA[NCO];
    __shared__ double coefB[NCO];
    __shared__ float xb[768];
    __shared__ float redf[1024];

    if (y == 2) {
        proj_256(sentence + b * 768, Ws, bs, final_ + b * 3840 + 2304, xb, redf, tid);
        return;
    }

    const bool scene = (y == 0);
    const float* kp = scene ? (scene_sent + b * 768) : (target + b * 768);
    const float* vp = scene ? (scene_desc + b * 768) : (target + b * 768);
    for (int i = tid; i < 768; i += 256) { kb[i] = kp[i]; vbuf[i] = vp[i]; }
    __syncthreads();

    const int lane = tid & 63;
    const int wid  = tid >> 6;
    const double k0 = (double)kb[tid], k1 = (double)kb[tid + 256], k2 = (double)kb[tid + 512];
    const double v0 = (double)vbuf[tid], v1 = (double)vbuf[tid + 256], v2 = (double)vbuf[tid + 512];
    double p0 = 1.0, p1 = 1.0, p2 = 1.0;

    #pragma unroll 2
    for (int n = 0; n < NPOW; ++n) {
        double su = (p0 + p1) + p2;
        su = wred(su);
        double sw = 0.0;
        if (scene) {
            sw = fma(p0, v0, fma(p1, v1, p2 * v2));
            sw = wred(sw);
        }
        if (lane == 0) { part[n][wid][0] = su; part[n][wid][1] = sw; }
        p0 *= k0; p1 *= k1; p2 *= k2;
    }
    __syncthreads();

    if (tid < NCO) {
        double fact = 1.0;
        for (int i = 2; i <= tid; ++i) fact *= (double)i;
        const double inv = 1.0 / fact;
        const double S = part[tid][0][0] + part[tid][1][0] + part[tid][2][0] + part[tid][3][0];
        coefA[tid] = S * inv;
        if (scene) {
            const double T = part[tid][0][1] + part[tid][1][1] + part[tid][2][1] + part[tid][3][1];
            coefB[tid] = T * inv;
        } else {
            const double S1 = part[tid + 1][0][0] + part[tid + 1][1][0]
                            + part[tid + 1][2][0] + part[tid + 1][3][0];
            coefB[tid] = S1 * inv;
        }
    }
    __syncthreads();

    // eval 3 rows/thread: num(q)/den(q) via Horner over 85 coefficients
    double q[3], num[3], den[3];
    #pragma unroll
    for (int j = 0; j < 3; ++j) {
        const int r = tid + 256 * j;
        q[j] = scene ? (double)kb[r] : (double)other[b * 768 + r];
        den[j] = coefA[NCO - 1];
        num[j] = coefB[NCO - 1];
    }
    for (int n = NCO - 2; n >= 0; --n) {
        const double a = coefA[n], c = coefB[n];
        #pragma unroll
        for (int j = 0; j < 3; ++j) {
            den[j] = fma(den[j], q[j], a);
            num[j] = fma(num[j], q[j], c);
        }
    }
    #pragma unroll
    for (int j = 0; j < 3; ++j)
        ctx[b * 1536 + (scene ? 0 : 768) + tid + 256 * j] = (float)(num[j] / den[j]);
}

// K2: grid (32,3), 256 threads.
//  y=0: fused self-attn over f=[sentence|ctx] via S_n = Σ f^n (q=k=v=f)
//  y=1,2: ctx projections
__global__ __launch_bounds__(256) void k2_fused_kernel(
    const float* __restrict__ sentence,
    const float* __restrict__ ctx,
    const float* __restrict__ Ws,
    const float* __restrict__ bs,
    float* __restrict__ final_)
{
    const int b = blockIdx.x;
    const int y = blockIdx.y;
    const int tid = threadIdx.x;
    __shared__ float fb[2304];
    __shared__ double part[NPOW][4];
    __shared__ double coefA[NCO];
    __shared__ double coefB[NCO];
    __shared__ float redf[1024];

    if (y > 0) {
        proj_256(ctx + b * 1536 + (y - 1) * 768, Ws, bs,
                 final_ + b * 3840 + 2304 + y * 512, fb, redf, tid);
        return;
    }

    for (int i = tid; i < 2304; i += 256)
        fb[i] = (i < 768) ? sentence[b * 768 + i] : ctx[b * 1536 + (i - 768)];
    __syncthreads();

    const int lane = tid & 63;
    const int wid  = tid >> 6;
    double kv[9], pw[9];
    #pragma unroll
    for (int j = 0; j < 9; ++j) { kv[j] = (double)fb[tid + 256 * j]; pw[j] = 1.0; }

    #pragma unroll 2
    for (int n = 0; n < NPOW; ++n) {
        double su = ((pw[0] + pw[1]) + (pw[2] + pw[3]))
                  + ((pw[4] + pw[5]) + (pw[6] + pw[7])) + pw[8];
        su = wred(su);
        if (lane == 0) part[n][wid] = su;
        #pragma unroll
        for (int j = 0; j < 9; ++j) pw[j] *= kv[j];
    }
    __syncthreads();

    if (tid < NCO) {
        double fact = 1.0;
        for (int i = 2; i <= tid; ++i) fact *= (double)i;
        const double inv = 1.0 / fact;
        const double S  = part[tid][0] + part[tid][1] + part[tid][2] + part[tid][3];
        const double S1 = part[tid + 1][0] + part[tid + 1][1] + part[tid + 1][2] + part[tid + 1][3];
        coefA[tid] = S * inv;
        coefB[tid] = S1 * inv;
    }
    __syncthreads();

    // eval 9 rows/thread (row values == this thread's staged f values)
    double num[9], den[9];
    #pragma unroll
    for (int j = 0; j < 9; ++j) { den[j] = coefA[NCO - 1]; num[j] = coefB[NCO - 1]; }
    for (int n = NCO - 2; n >= 0; --n) {
        const double a = coefA[n], c = coefB[n];
        #pragma unroll
        for (int j = 0; j < 9; ++j) {
            den[j] = fma(den[j], kv[j], a);
            num[j] = fma(num[j], kv[j], c);
        }
    }
    #pragma unroll
    for (int j = 0; j < 9; ++j)
        final_[b * 3840 + tid + 256 * j] = (float)(num[j] / den[j]);
}

// MLP stage 1, K-split across blocks: grid (32,8), 1024 threads.
__global__ __launch_bounds__(1024) void mlp_part_kernel(
    const float* __restrict__ final_,
    const float* __restrict__ W1,   // [3840, 256]
    float* __restrict__ hpart)      // [32][8][256]
{
    const int b = blockIdx.x;
    const int c = blockIdx.y;
    const int tid = threadIdx.x;
    const int base = c * 480;

    __shared__ float fb[480];
    __shared__ float red[16][256];
    if (tid < 480) fb[tid] = final_[b * 3840 + base + tid];
    __syncthreads();

    const int g = tid >> 6;         // wave id, 16 waves
    const int q = tid & 63;         // column quad
    const float4* __restrict__ Wv = (const float4*)W1;   // [3840][64]
    float ax = 0.f, ay = 0.f, az = 0.f, aw = 0.f;
    const int l0 = g * 30;
    #pragma unroll 5
    for (int kk = 0; kk < 30; ++kk) {
        const float xv = fb[l0 + kk];
        const float4 w = Wv[(base + l0 + kk) * 64 + q];
        ax += xv * w.x; ay += xv * w.y; az += xv * w.z; aw += xv * w.w;
    }
    red[g][q * 4 + 0] = ax;
    red[g][q * 4 + 1] = ay;
    red[g][q * 4 + 2] = az;
    red[g][q * 4 + 3] = aw;
    __syncthreads();

    if (tid < 256) {
        float s = 0.f;
        #pragma unroll
        for (int g2 = 0; g2 < 16; ++g2) s += red[g2][tid];
        hpart[(b * 8 + c) * 256 + tid] = s;
    }
}

// MLP tail: combine K-partials, relu, [256x7] head, sigmoid. grid 32, 512 threads.
__global__ __launch_bounds__(512) void mlp_tail_kernel(
    const float* __restrict__ hpart,
    const float* __restrict__ b1,
    const float* __restrict__ W2,   // [256, 7]
    const float* __restrict__ b2,
    float* __restrict__ out)        // [32, 7]
{
    const int b = blockIdx.x;
    const int tid = threadIdx.x;

    __shared__ float hb[256];
    if (tid < 256) {
        float s = b1[tid];
        #pragma unroll
        for (int c = 0; c < 8; ++c) s += hpart[(b * 8 + c) * 256 + tid];
        hb[tid] = fmaxf(s, 0.f);
    }
    __syncthreads();

    const int w = tid >> 6;
    const int lane = tid & 63;
    if (w < 7) {
        float a = 0.f;
        #pragma unroll
        for (int c = lane; c < 256; c += 64)
            a += hb[c] * W2[c * 7 + w];
        #pragma unroll
        for (int off = 32; off > 0; off >>= 1)
            a += __shfl_down(a, off, 64);
        if (lane == 0)
            out[b * 7 + w] = 1.f / (1.f + __expf(-(a + b2[w])));
    }
}

extern "C" void kernel_launch(void* const* d_in, const int* in_sizes, int n_in,
                              void* d_out, int out_size, void* d_ws, size_t ws_size,
                              hipStream_t stream) {
    const float* sentence   = (const float*)d_in[0];
    const float* target     = (const float*)d_in[1];
    const float* other      = (const float*)d_in[2];
    const float* scene_desc = (const float*)d_in[3];
    const float* scene_sent = (const float*)d_in[4];
    const float* Ws         = (const float*)d_in[5];
    const float* bs         = (const float*)d_in[6];
    const float* W1         = (const float*)d_in[7];
    const float* b1         = (const float*)d_in[8];
    const float* W2         = (const float*)d_in[9];
    const float* b2         = (const float*)d_in[10];
    float* out = (float*)d_out;

    float* ctx    = (float*)d_ws;             // 32*1536 floats
    float* final_ = ctx + 32 * 1536;          // 32*3840 floats
    float* hpart  = final_ + 32 * 3840;       // 32*8*256 floats

    k1_small_kernel<<<dim3(32, 3), 256, 0, stream>>>(sentence, target, other,
                                                     scene_desc, scene_sent,
                                                     Ws, bs, ctx, final_);
    k2_fused_kernel<<<dim3(32, 3), 256, 0, stream>>>(sentence, ctx, Ws, bs, final_);
    mlp_part_kernel<<<dim3(32, 8), 1024, 0, stream>>>(final_, W1, hpart);
    mlp_tail_kernel<<<32, 512, 0, stream>>>(hpart, b1, W2, b2, out);
}

// Round 12
// 52.515 us; speedup vs baseline: 1.7965x; 1.7965x over previous
//
#include <hip/hip_runtime.h>
#include <math.h>

#define NPOW 88   // power sums S_0..S_87
#define NCO  85   // series coefficients n=0..84

// ws layout:
//   ctx   [32][2][768]  : scene_context | speaker_context
//   final [32][3840]    : [z(2304) | sent_sh(512) | scene_sh(512) | spkr_sh(512)]
//   hpart [32][8][256]  : mlp stage-1 K-split partials

// ---- projection helper: [768] x [768,512] with 256 threads, 2-way K-split
__device__ __forceinline__ void proj_256(
    const float* __restrict__ xsrc,
    const float* __restrict__ Ws,            // [768, 512]
    const float* __restrict__ bs,            // [512]
    float* __restrict__ dst,
    float* xb,                               // LDS [768]
    float* redf,                             // LDS [1024] = [2][512]
    int tid)
{
    for (int i = tid; i < 768; i += 256) xb[i] = xsrc[i];
    __syncthreads();

    const int g = tid >> 7;        // 0..1
    const int q = tid & 127;       // column quad
    const float4* __restrict__ Wv = (const float4*)Ws;   // [768][128]
    float ax = 0.f, ay = 0.f, az = 0.f, aw = 0.f;
    #pragma unroll 8
    for (int k = g; k < 768; k += 2) {
        const float xv = xb[k];
        const float4 w = Wv[k * 128 + q];
        ax += xv * w.x; ay += xv * w.y; az += xv * w.z; aw += xv * w.w;
    }
    redf[g * 512 + q * 4 + 0] = ax;
    redf[g * 512 + q * 4 + 1] = ay;
    redf[g * 512 + q * 4 + 2] = az;
    redf[g * 512 + q * 4 + 3] = aw;
    __syncthreads();

    dst[tid]       = bs[tid]       + redf[tid]       + redf[512 + tid];
    dst[tid + 256] = bs[tid + 256] + redf[tid + 256] + redf[512 + tid + 256];
}

// 5-step intra-32-lane reduce (xor bits 1..16 stay within each 32-lane half)
__device__ __forceinline__ double red32(double x) {
    x += __shfl_xor(x, 1, 64);
    x += __shfl_xor(x, 2, 64);
    x += __shfl_xor(x, 4, 64);
    x += __shfl_xor(x, 8, 64);
    x += __shfl_xor(x, 16, 64);
    return x;
}

// K1: grid (32,3), 256 threads.
//  y=0: scene ctx  = attn(q=ss, k=ss, v=sd): S_n = sum ss^n, T_n = sum ss^n*sd
//  y=1: spkr ctx   = attn(q=oth, k=tgt, v=tgt): S_n only (num uses S_{n+1})
//  y=2: sentence projection
__global__ __launch_bounds__(256) void k1_small_kernel(
    const float* __restrict__ sentence,
    const float* __restrict__ target,
    const float* __restrict__ other,
    const float* __restrict__ scene_desc,
    const float* __restrict__ scene_sent,
    const float* __restrict__ Ws,
    const float* __restrict__ bs,
    float* __restrict__ ctx,
    float* __restrict__ final_)
{
    const int b = blockIdx.x;
    const int y = blockIdx.y;
    const int tid = threadIdx.x;
    __shared__ float kb[768];
    __shared__ float vbuf[768];
    __shared__ double redbuf[2][2048];
    __shared__ double part[NPOW][2];
    __shared__ double coefA[NCO];
    __shared__ double coefB[NCO];
    __shared__ float redf[1024];

    if (y == 2) {
        proj_256(sentence + b * 768, Ws, bs, final_ + b * 3840 + 2304, kb, redf, tid);
        return;
    }

    const bool scene = (y == 0);
    const float* kp = scene ? (scene_sent + b * 768) : (target + b * 768);
    const float* vp = scene ? (scene_desc + b * 768) : (target + b * 768);
    for (int i = tid; i < 768; i += 256) { kb[i] = kp[i]; vbuf[i] = vp[i]; }
    __syncthreads();

    const double k0 = (double)kb[tid], k1 = (double)kb[tid + 256], k2 = (double)kb[tid + 512];
    const double v0 = (double)vbuf[tid], v1 = (double)vbuf[tid + 256], v2 = (double)vbuf[tid + 512];
    double p0 = 1.0, p1 = 1.0, p2 = 1.0;

    if (scene) {
        // 22 chunks x 4 powers, 2 sums each
        for (int c = 0; c < 22; ++c) {
            double* buf = redbuf[c & 1];
            #pragma unroll
            for (int m = 0; m < 4; ++m) {
                buf[(m * 2 + 0) * 256 + tid] = (p0 + p1) + p2;
                buf[(m * 2 + 1) * 256 + tid] = fma(p0, v0, fma(p1, v1, p2 * v2));
                p0 *= k0; p1 *= k1; p2 *= k2;
            }
            __syncthreads();
            const int n = tid >> 6;          // 0..3
            const int s = (tid >> 5) & 1;    // 0..1
            const int l = tid & 31;
            const double* src = buf + (n * 2 + s) * 256 + l;
            double acc = ((src[0] + src[32]) + (src[64] + src[96]))
                       + ((src[128] + src[160]) + (src[192] + src[224]));
            acc = red32(acc);
            if (l == 0) part[c * 4 + n][s] = acc;
        }
    } else {
        // 11 chunks x 8 powers, 1 sum each
        for (int c = 0; c < 11; ++c) {
            double* buf = redbuf[c & 1];
            #pragma unroll
            for (int m = 0; m < 8; ++m) {
                buf[m * 256 + tid] = (p0 + p1) + p2;
                p0 *= k0; p1 *= k1; p2 *= k2;
            }
            __syncthreads();
            const int n = tid >> 5;          // 0..7
            const int l = tid & 31;
            const double* src = buf + n * 256 + l;
            double acc = ((src[0] + src[32]) + (src[64] + src[96]))
                       + ((src[128] + src[160]) + (src[192] + src[224]));
            acc = red32(acc);
            if (l == 0) part[c * 8 + n][0] = acc;
        }
    }
    __syncthreads();

    if (tid < NCO) {
        double fact = 1.0;
        for (int i = 2; i <= tid; ++i) fact *= (double)i;
        const double inv = 1.0 / fact;
        coefA[tid] = part[tid][0] * inv;
        coefB[tid] = scene ? (part[tid][1] * inv) : (part[tid + 1][0] * inv);
    }
    __syncthreads();

    // eval 3 rows/thread: num(q)/den(q) via Horner over 85 coefficients
    double q[3], num[3], den[3];
    #pragma unroll
    for (int j = 0; j < 3; ++j) {
        const int r = tid + 256 * j;
        q[j] = scene ? (double)kb[r] : (double)other[b * 768 + r];
        den[j] = coefA[NCO - 1];
        num[j] = coefB[NCO - 1];
    }
    for (int n = NCO - 2; n >= 0; --n) {
        const double a = coefA[n], cc = coefB[n];
        #pragma unroll
        for (int j = 0; j < 3; ++j) {
            den[j] = fma(den[j], q[j], a);
            num[j] = fma(num[j], q[j], cc);
        }
    }
    #pragma unroll
    for (int j = 0; j < 3; ++j)
        ctx[b * 1536 + (scene ? 0 : 768) + tid + 256 * j] = (float)(num[j] / den[j]);
}

// K2: grid (32,3), 256 threads.
//  y=0: fused self-attn over f=[sentence|ctx]: S_n = sum f^n (q=k=v=f)
//  y=1,2: ctx projections
__global__ __launch_bounds__(256) void k2_fused_kernel(
    const float* __restrict__ sentence,
    const float* __restrict__ ctx,
    const float* __restrict__ Ws,
    const float* __restrict__ bs,
    float* __restrict__ final_)
{
    const int b = blockIdx.x;
    const int y = blockIdx.y;
    const int tid = threadIdx.x;
    __shared__ float fb[2304];
    __shared__ double redbuf[2][2048];
    __shared__ double part[NPOW];
    __shared__ double coefA[NCO];
    __shared__ double coefB[NCO];
    __shared__ float redf[1024];

    if (y > 0) {
        proj_256(ctx + b * 1536 + (y - 1) * 768, Ws, bs,
                 final_ + b * 3840 + 2304 + y * 512, fb, redf, tid);
        return;
    }

    for (int i = tid; i < 2304; i += 256)
        fb[i] = (i < 768) ? sentence[b * 768 + i] : ctx[b * 1536 + (i - 768)];
    __syncthreads();

    double kv[9], pw[9];
    #pragma unroll
    for (int j = 0; j < 9; ++j) { kv[j] = (double)fb[tid + 256 * j]; pw[j] = 1.0; }

    for (int c = 0; c < 11; ++c) {
        double* buf = redbuf[c & 1];
        #pragma unroll
        for (int m = 0; m < 8; ++m) {
            buf[m * 256 + tid] = (((pw[0] + pw[1]) + (pw[2] + pw[3]))
                                + ((pw[4] + pw[5]) + (pw[6] + pw[7]))) + pw[8];
            #pragma unroll
            for (int j = 0; j < 9; ++j) pw[j] *= kv[j];
        }
        __syncthreads();
        const int n = tid >> 5;
        const int l = tid & 31;
        const double* src = buf + n * 256 + l;
        double acc = ((src[0] + src[32]) + (src[64] + src[96]))
                   + ((src[128] + src[160]) + (src[192] + src[224]));
        acc = red32(acc);
        if (l == 0) part[c * 8 + n] = acc;
    }
    __syncthreads();

    if (tid < NCO) {
        double fact = 1.0;
        for (int i = 2; i <= tid; ++i) fact *= (double)i;
        const double inv = 1.0 / fact;
        coefA[tid] = part[tid] * inv;
        coefB[tid] = part[tid + 1] * inv;
    }
    __syncthreads();

    // eval 9 rows/thread (row q values == this thread's staged f values)
    double num[9], den[9];
    #pragma unroll
    for (int j = 0; j < 9; ++j) { den[j] = coefA[NCO - 1]; num[j] = coefB[NCO - 1]; }
    for (int n = NCO - 2; n >= 0; --n) {
        const double a = coefA[n], cc = coefB[n];
        #pragma unroll
        for (int j = 0; j < 9; ++j) {
            den[j] = fma(den[j], kv[j], a);
            num[j] = fma(num[j], kv[j], cc);
        }
    }
    #pragma unroll
    for (int j = 0; j < 9; ++j)
        final_[b * 3840 + tid + 256 * j] = (float)(num[j] / den[j]);
}

// MLP stage 1, K-split across blocks: grid (32,8), 1024 threads.
__global__ __launch_bounds__(1024) void mlp_part_kernel(
    const float* __restrict__ final_,
    const float* __restrict__ W1,   // [3840, 256]
    float* __restrict__ hpart)      // [32][8][256]
{
    const int b = blockIdx.x;
    const int c = blockIdx.y;
    const int tid = threadIdx.x;
    const int base = c * 480;

    __shared__ float fb[480];
    __shared__ float red[16][256];
    if (tid < 480) fb[tid] = final_[b * 3840 + base + tid];
    __syncthreads();

    const int g = tid >> 6;         // wave id, 16 waves
    const int q = tid & 63;         // column quad
    const float4* __restrict__ Wv = (const float4*)W1;   // [3840][64]
    float ax = 0.f, ay = 0.f, az = 0.f, aw = 0.f;
    const int l0 = g * 30;
    #pragma unroll 5
    for (int kk = 0; kk < 30; ++kk) {
        const float xv = fb[l0 + kk];
        const float4 w = Wv[(base + l0 + kk) * 64 + q];
        ax += xv * w.x; ay += xv * w.y; az += xv * w.z; aw += xv * w.w;
    }
    red[g][q * 4 + 0] = ax;
    red[g][q * 4 + 1] = ay;
    red[g][q * 4 + 2] = az;
    red[g][q * 4 + 3] = aw;
    __syncthreads();

    if (tid < 256) {
        float s = 0.f;
        #pragma unroll
        for (int g2 = 0; g2 < 16; ++g2) s += red[g2][tid];
        hpart[(b * 8 + c) * 256 + tid] = s;
    }
}

// MLP tail: combine K-partials, relu, [256x7] head, sigmoid. grid 32, 512 threads.
__global__ __launch_bounds__(512) void mlp_tail_kernel(
    const float* __restrict__ hpart,
    const float* __restrict__ b1,
    const float* __restrict__ W2,   // [256, 7]
    const float* __restrict__ b2,
    float* __restrict__ out)        // [32, 7]
{
    const int b = blockIdx.x;
    const int tid = threadIdx.x;

    __shared__ float hb[256];
    if (tid < 256) {
        float s = b1[tid];
        #pragma unroll
        for (int c = 0; c < 8; ++c) s += hpart[(b * 8 + c) * 256 + tid];
        hb[tid] = fmaxf(s, 0.f);
    }
    __syncthreads();

    const int w = tid >> 6;
    const int lane = tid & 63;
    if (w < 7) {
        float a = 0.f;
        #pragma unroll
        for (int c = lane; c < 256; c += 64)
            a += hb[c] * W2[c * 7 + w];
        #pragma unroll
        for (int off = 32; off > 0; off >>= 1)
            a += __shfl_down(a, off, 64);
        if (lane == 0)
            out[b * 7 + w] = 1.f / (1.f + __expf(-(a + b2[w])));
    }
}

extern "C" void kernel_launch(void* const* d_in, const int* in_sizes, int n_in,
                              void* d_out, int out_size, void* d_ws, size_t ws_size,
                              hipStream_t stream) {
    const float* sentence   = (const float*)d_in[0];
    const float* target     = (const float*)d_in[1];
    const float* other      = (const float*)d_in[2];
    const float* scene_desc = (const float*)d_in[3];
    const float* scene_sent = (const float*)d_in[4];
    const float* Ws         = (const float*)d_in[5];
    const float* bs         = (const float*)d_in[6];
    const float* W1         = (const float*)d_in[7];
    const float* b1         = (const float*)d_in[8];
    const float* W2         = (const float*)d_in[9];
    const float* b2         = (const float*)d_in[10];
    float* out = (float*)d_out;

    float* ctx    = (float*)d_ws;             // 32*1536 floats
    float* final_ = ctx + 32 * 1536;          // 32*3840 floats
    float* hpart  = final_ + 32 * 3840;       // 32*8*256 floats

    k1_small_kernel<<<dim3(32, 3), 256, 0, stream>>>(sentence, target, other,
                                                     scene_desc, scene_sent,
                                                     Ws, bs, ctx, final_);
    k2_fused_kernel<<<dim3(32, 3), 256, 0, stream>>>(sentence, ctx, Ws, bs, final_);
    mlp_part_kernel<<<dim3(32, 8), 1024, 0, stream>>>(final_, W1, hpart);
    mlp_tail_kernel<<<32, 512, 0, stream>>>(hpart, b1, W2, b2, out);
}

// Round 13
// 50.664 us; speedup vs baseline: 1.8622x; 1.0365x over previous
//
#include <hip/hip_runtime.h>
#include <math.h>

// Moment-method attention (d=1): e^{qf} = sum_n (qf)^n/n!  ->  per batch compute
// power sums once, evaluate num/den polynomials per row.  Rescale g = f/4 so all
// power sums fit f32 (scan in f32); coefficients + Horner in f64 with x = 4q.
//
// ws layout:
//   ctx   [32][2][768]  : scene_context | speaker_context
//   final [32][3840]    : [z(2304) | sent_sh(512) | scene_sh(512) | spkr_sh(512)]
//   hpart [32][8][256]  : mlp stage-1 K-split partials

#define NPOW 88
#define NCO  85

__device__ __forceinline__ float red32f(float x) {
    x += __shfl_xor(x, 1, 64);
    x += __shfl_xor(x, 2, 64);
    x += __shfl_xor(x, 4, 64);
    x += __shfl_xor(x, 8, 64);
    x += __shfl_xor(x, 16, 64);
    return x;
}

// ---- projection helper: [768] x [768,512] with 256 threads, 2-way K-split
__device__ __forceinline__ void proj_256(
    const float* __restrict__ xsrc,
    const float* __restrict__ Ws,            // [768, 512]
    const float* __restrict__ bs,            // [512]
    float* __restrict__ dst,
    float* xb,                               // LDS [768]
    float* redf,                             // LDS [1024] = [2][512]
    int tid)
{
    for (int i = tid; i < 768; i += 256) xb[i] = xsrc[i];
    __syncthreads();

    const int g = tid >> 7;        // 0..1
    const int q = tid & 127;       // column quad
    const float4* __restrict__ Wv = (const float4*)Ws;   // [768][128]
    float ax = 0.f, ay = 0.f, az = 0.f, aw = 0.f;
    #pragma unroll 8
    for (int k = g; k < 768; k += 2) {
        const float xv = xb[k];
        const float4 w = Wv[k * 128 + q];
        ax += xv * w.x; ay += xv * w.y; az += xv * w.z; aw += xv * w.w;
    }
    redf[g * 512 + q * 4 + 0] = ax;
    redf[g * 512 + q * 4 + 1] = ay;
    redf[g * 512 + q * 4 + 2] = az;
    redf[g * 512 + q * 4 + 3] = aw;
    __syncthreads();

    dst[tid]       = bs[tid]       + redf[tid]       + redf[512 + tid];
    dst[tid + 256] = bs[tid + 256] + redf[tid + 256] + redf[512 + tid + 256];
}

// K1: grid (32,7), 256 threads.
//  y=0..2: scene ctx slices  (q=ss, k=ss, v=sd): S'_n = sum g^n, T'_n = sum g^n*v
//  y=3..5: speaker ctx slices (q=oth, k=v=tgt): S'_n only (num uses S'_{n+1}, x4)
//  y=6: sentence projection
__global__ __launch_bounds__(256) void k1_small_kernel(
    const float* __restrict__ sentence,
    const float* __restrict__ target,
    const float* __restrict__ other,
    const float* __restrict__ scene_desc,
    const float* __restrict__ scene_sent,
    const float* __restrict__ Ws,
    const float* __restrict__ bs,
    float* __restrict__ ctx,
    float* __restrict__ final_)
{
    const int b = blockIdx.x;
    const int y = blockIdx.y;
    const int tid = threadIdx.x;
    __shared__ float kb[768];
    __shared__ float vbuf[768];
    __shared__ float redbuf[2][2048];
    __shared__ float partS[NPOW];
    __shared__ float partT[NPOW];
    __shared__ double coefA[NCO];
    __shared__ double coefB[NCO];
    __shared__ float redf[1024];

    if (y == 6) {
        proj_256(sentence + b * 768, Ws, bs, final_ + b * 3840 + 2304, kb, redf, tid);
        return;
    }

    const bool scene = (y < 3);
    const float* kp = scene ? (scene_sent + b * 768) : (target + b * 768);
    const float* vp = scene ? (scene_desc + b * 768) : (target + b * 768);
    for (int i = tid; i < 768; i += 256) { kb[i] = kp[i]; vbuf[i] = vp[i]; }
    __syncthreads();

    const float g0 = kb[tid] * 0.25f, g1 = kb[tid + 256] * 0.25f, g2 = kb[tid + 512] * 0.25f;
    float p0 = 1.f, p1 = 1.f, p2 = 1.f;

    if (scene) {
        const float v0 = vbuf[tid], v1 = vbuf[tid + 256], v2 = vbuf[tid + 512];
        for (int c = 0; c < 22; ++c) {
            float* buf = redbuf[c & 1];
            #pragma unroll
            for (int m = 0; m < 4; ++m) {
                buf[(m * 2 + 0) * 256 + tid] = (p0 + p1) + p2;
                buf[(m * 2 + 1) * 256 + tid] = fmaf(p0, v0, fmaf(p1, v1, p2 * v2));
                p0 *= g0; p1 *= g1; p2 *= g2;
            }
            __syncthreads();
            const int n = tid >> 6, s = (tid >> 5) & 1, l = tid & 31;
            const float* src = buf + (n * 2 + s) * 256 + l;
            float acc = ((src[0] + src[32]) + (src[64] + src[96]))
                      + ((src[128] + src[160]) + (src[192] + src[224]));
            acc = red32f(acc);
            if (l == 0) { if (s == 0) partS[c * 4 + n] = acc; else partT[c * 4 + n] = acc; }
        }
    } else {
        for (int c = 0; c < 11; ++c) {
            float* buf = redbuf[c & 1];
            #pragma unroll
            for (int m = 0; m < 8; ++m) {
                buf[m * 256 + tid] = (p0 + p1) + p2;
                p0 *= g0; p1 *= g1; p2 *= g2;
            }
            __syncthreads();
            const int n = tid >> 5, l = tid & 31;
            const float* src = buf + n * 256 + l;
            float acc = ((src[0] + src[32]) + (src[64] + src[96]))
                      + ((src[128] + src[160]) + (src[192] + src[224]));
            acc = red32f(acc);
            if (l == 0) partS[c * 8 + n] = acc;
        }
    }
    __syncthreads();

    if (tid < NCO) {
        double fact = 1.0;
        for (int i = 2; i <= tid; ++i) fact *= (double)i;
        const double inv = 1.0 / fact;
        coefA[tid] = (double)partS[tid] * inv;
        coefB[tid] = scene ? ((double)partT[tid] * inv) : ((double)partS[tid + 1] * inv);
    }
    __syncthreads();

    const int slice = scene ? y : (y - 3);
    const int r = slice * 256 + tid;
    const double x = 4.0 * (double)(scene ? kb[r] : other[b * 768 + r]);
    double den = coefA[NCO - 1], num = coefB[NCO - 1];
    for (int n = NCO - 2; n >= 0; --n) {
        den = fma(den, x, coefA[n]);
        num = fma(num, x, coefB[n]);
    }
    const double ratio = scene ? (num / den) : (4.0 * num / den);
    ctx[b * 1536 + (scene ? 0 : 768) + r] = (float)ratio;
}

// K2: grid (32,11), 256 threads.
//  y=0..8: fused self-attn slices over f=[sentence|ctx] (q=k=v=f)
//  y=9,10: ctx projections
__global__ __launch_bounds__(256) void k2_fused_kernel(
    const float* __restrict__ sentence,
    const float* __restrict__ ctx,
    const float* __restrict__ Ws,
    const float* __restrict__ bs,
    float* __restrict__ final_)
{
    const int b = blockIdx.x;
    const int y = blockIdx.y;
    const int tid = threadIdx.x;
    __shared__ float fb[2304];
    __shared__ float redbuf[2][2048];
    __shared__ float partS[NPOW];
    __shared__ double coefA[NCO];
    __shared__ double coefB[NCO];
    __shared__ float redf[1024];

    if (y >= 9) {
        const int p = y - 8;     // 1 or 2
        proj_256(ctx + b * 1536 + (p - 1) * 768, Ws, bs,
                 final_ + b * 3840 + 2304 + p * 512, fb, redf, tid);
        return;
    }

    for (int i = tid; i < 2304; i += 256)
        fb[i] = (i < 768) ? sentence[b * 768 + i] : ctx[b * 1536 + (i - 768)];
    __syncthreads();

    float g[9], pw[9];
    #pragma unroll
    for (int j = 0; j < 9; ++j) { g[j] = fb[tid + 256 * j] * 0.25f; pw[j] = 1.f; }

    for (int c = 0; c < 11; ++c) {
        float* buf = redbuf[c & 1];
        #pragma unroll
        for (int m = 0; m < 8; ++m) {
            buf[m * 256 + tid] = (((pw[0] + pw[1]) + (pw[2] + pw[3]))
                                + ((pw[4] + pw[5]) + (pw[6] + pw[7]))) + pw[8];
            #pragma unroll
            for (int j = 0; j < 9; ++j) pw[j] *= g[j];
        }
        __syncthreads();
        const int n = tid >> 5, l = tid & 31;
        const float* src = buf + n * 256 + l;
        float acc = ((src[0] + src[32]) + (src[64] + src[96]))
                  + ((src[128] + src[160]) + (src[192] + src[224]));
        acc = red32f(acc);
        if (l == 0) partS[c * 8 + n] = acc;
    }
    __syncthreads();

    if (tid < NCO) {
        double fact = 1.0;
        for (int i = 2; i <= tid; ++i) fact *= (double)i;
        const double inv = 1.0 / fact;
        coefA[tid] = (double)partS[tid] * inv;
        coefB[tid] = (double)partS[tid + 1] * inv;
    }
    __syncthreads();

    const int r = y * 256 + tid;
    const double x = 4.0 * (double)fb[r];
    double den = coefA[NCO - 1], num = coefB[NCO - 1];
    for (int n = NCO - 2; n >= 0; --n) {
        den = fma(den, x, coefA[n]);
        num = fma(num, x, coefB[n]);
    }
    final_[b * 3840 + r] = (float)(4.0 * num / den);
}

// MLP stage 1, K-split across blocks: grid (32,8), 1024 threads.
__global__ __launch_bounds__(1024) void mlp_part_kernel(
    const float* __restrict__ final_,
    const float* __restrict__ W1,   // [3840, 256]
    float* __restrict__ hpart)      // [32][8][256]
{
    const int b = blockIdx.x;
    const int c = blockIdx.y;
    const int tid = threadIdx.x;
    const int base = c * 480;

    __shared__ float fb[480];
    __shared__ float red[16][256];
    if (tid < 480) fb[tid] = final_[b * 3840 + base + tid];
    __syncthreads();

    const int g = tid >> 6;         // wave id, 16 waves
    const int q = tid & 63;         // column quad
    const float4* __restrict__ Wv = (const float4*)W1;   // [3840][64]
    float ax = 0.f, ay = 0.f, az = 0.f, aw = 0.f;
    const int l0 = g * 30;
    #pragma unroll 5
    for (int kk = 0; kk < 30; ++kk) {
        const float xv = fb[l0 + kk];
        const float4 w = Wv[(base + l0 + kk) * 64 + q];
        ax += xv * w.x; ay += xv * w.y; az += xv * w.z; aw += xv * w.w;
    }
    red[g][q * 4 + 0] = ax;
    red[g][q * 4 + 1] = ay;
    red[g][q * 4 + 2] = az;
    red[g][q * 4 + 3] = aw;
    __syncthreads();

    if (tid < 256) {
        float s = 0.f;
        #pragma unroll
        for (int g2 = 0; g2 < 16; ++g2) s += red[g2][tid];
        hpart[(b * 8 + c) * 256 + tid] = s;
    }
}

// MLP tail: combine K-partials, relu, [256x7] head, sigmoid. grid 32, 512 threads.
__global__ __launch_bounds__(512) void mlp_tail_kernel(
    const float* __restrict__ hpart,
    const float* __restrict__ b1,
    const float* __restrict__ W2,   // [256, 7]
    const float* __restrict__ b2,
    float* __restrict__ out)        // [32, 7]
{
    const int b = blockIdx.x;
    const int tid = threadIdx.x;

    __shared__ float hb[256];
    if (tid < 256) {
        float s = b1[tid];
        #pragma unroll
        for (int c = 0; c < 8; ++c) s += hpart[(b * 8 + c) * 256 + tid];
        hb[tid] = fmaxf(s, 0.f);
    }
    __syncthreads();

    const int w = tid >> 6;
    const int lane = tid & 63;
    if (w < 7) {
        float a = 0.f;
        #pragma unroll
        for (int c = lane; c < 256; c += 64)
            a += hb[c] * W2[c * 7 + w];
        #pragma unroll
        for (int off = 32; off > 0; off >>= 1)
            a += __shfl_down(a, off, 64);
        if (lane == 0)
            out[b * 7 + w] = 1.f / (1.f + __expf(-(a + b2[w])));
    }
}

extern "C" void kernel_launch(void* const* d_in, const int* in_sizes, int n_in,
                              void* d_out, int out_size, void* d_ws, size_t ws_size,
                              hipStream_t stream) {
    const float* sentence   = (const float*)d_in[0];
    const float* target     = (const float*)d_in[1];
    const float* other      = (const float*)d_in[2];
    const float* scene_desc = (const float*)d_in[3];
    const float* scene_sent = (const float*)d_in[4];
    const float* Ws         = (const float*)d_in[5];
    const float* bs         = (const float*)d_in[6];
    const float* W1         = (const float*)d_in[7];
    const float* b1         = (const float*)d_in[8];
    const float* W2         = (const float*)d_in[9];
    const float* b2         = (const float*)d_in[10];
    float* out = (float*)d_out;

    float* ctx    = (float*)d_ws;             // 32*1536 floats
    float* final_ = ctx + 32 * 1536;          // 32*3840 floats
    float* hpart  = final_ + 32 * 3840;       // 32*8*256 floats

    k1_small_kernel<<<dim3(32, 7), 256, 0, stream>>>(sentence, target, other,
                                                     scene_desc, scene_sent,
                                                     Ws, bs, ctx, final_);
    k2_fused_kernel<<<dim3(32, 11), 256, 0, stream>>>(sentence, ctx, Ws, bs, final_);
    mlp_part_kernel<<<dim3(32, 8), 1024, 0, stream>>>(final_, W1, hpart);
    mlp_tail_kernel<<<32, 512, 0, stream>>>(hpart, b1, W2, b2, out);
}